// Round 1
// baseline (6066.512 us; speedup 1.0000x reference)
//
#include <hip/hip_runtime.h>

typedef unsigned short u16;
typedef short bfrag __attribute__((ext_vector_type(8)));   // 8 bf16 operand frag
typedef float f32x4 __attribute__((ext_vector_type(4)));   // MFMA accumulator

#define L_LAYERS 12
#define BATCH 32
#define NTOK 576
#define DMODEL 768
#define NHEAD 12
#define DHEAD 64
#define BN_ROWS (BATCH * NTOK)   // 18432
#define QKV_N (3 * DMODEL)       // 2304

__device__ __forceinline__ u16 f2bf(float f) {
    union { float f; unsigned u; } x; x.f = f;
    unsigned r = (x.u + 0x7FFFu + ((x.u >> 16) & 1u)) >> 16;
    return (u16)r;
}

// ---------------- transpose + fp32->bf16 cast: src[R][C] -> dst[C][R] ----------------
__global__ __launch_bounds__(256) void transpose_cast_kernel(
        const float* __restrict__ src, u16* __restrict__ dst, int R, int C) {
    __shared__ u16 tile[64][65];
    int c0 = blockIdx.x * 64, r0 = blockIdx.y * 64;
    int tid = threadIdx.x;
    for (int i = tid; i < 4096; i += 256) {
        int rr = i >> 6, cc = i & 63;
        tile[rr][cc] = f2bf(src[(size_t)(r0 + rr) * C + c0 + cc]);
    }
    __syncthreads();
    for (int i = tid; i < 4096; i += 256) {
        int cc = i >> 6, rr = i & 63;
        dst[(size_t)(c0 + cc) * R + r0 + rr] = tile[rr][cc];
    }
}

// ---------------- LayerNorm: fp32 z row -> bf16 out row (one row per wave) ----------------
__global__ __launch_bounds__(256) void ln_kernel(
        const float* __restrict__ z, const float* __restrict__ g,
        const float* __restrict__ b, u16* __restrict__ out) {
    int w = threadIdx.x >> 6, lane = threadIdx.x & 63;
    int row = blockIdx.x * 4 + w;
    const float* zr = z + (size_t)row * DMODEL;
    float4 v[3];
    float sum = 0.f, sq = 0.f;
#pragma unroll
    for (int c = 0; c < 3; ++c) {
        v[c] = *(const float4*)(zr + c * 256 + lane * 4);
        sum += v[c].x + v[c].y + v[c].z + v[c].w;
        sq  += v[c].x * v[c].x + v[c].y * v[c].y + v[c].z * v[c].z + v[c].w * v[c].w;
    }
#pragma unroll
    for (int m = 1; m < 64; m <<= 1) {
        sum += __shfl_xor(sum, m);
        sq  += __shfl_xor(sq, m);
    }
    float mean = sum * (1.0f / DMODEL);
    float var  = sq * (1.0f / DMODEL) - mean * mean;
    float inv  = 1.0f / sqrtf(var + 1e-5f);
    u16* orow = out + (size_t)row * DMODEL;
#pragma unroll
    for (int c = 0; c < 3; ++c) {
        int col = c * 256 + lane * 4;
        float4 gg = *(const float4*)(g + col);
        float4 bb = *(const float4*)(b + col);
        ushort4 u;
        u.x = f2bf((v[c].x - mean) * inv * gg.x + bb.x);
        u.y = f2bf((v[c].y - mean) * inv * gg.y + bb.y);
        u.z = f2bf((v[c].z - mean) * inv * gg.z + bb.z);
        u.w = f2bf((v[c].w - mean) * inv * gg.w + bb.w);
        *(ushort4*)(orow + col) = u;
    }
}

// ---------------- bf16 MFMA GEMM: C[M][N] = A[M][K] @ Bt[N][K]^T ----------------
// MODE 0: store bf16 to obf.  MODE 1: zres[row][col] += acc + bias[col].
template<int MODE>
__global__ __launch_bounds__(256) void gemm_kernel(
        const u16* __restrict__ A, const u16* __restrict__ Bt,
        int M, int N, int K,
        u16* __restrict__ obf, const float* __restrict__ bias, float* __restrict__ zres) {
    __shared__ __attribute__((aligned(16))) u16 As[128 * 40];
    __shared__ __attribute__((aligned(16))) u16 Bs[128 * 40];
    int tid = threadIdx.x;
    int lane = tid & 63, w = tid >> 6;
    int wr = w >> 1, wc = w & 1;
    int r = lane & 15, gq = lane >> 4;
    int m0 = blockIdx.y * 128, n0 = blockIdx.x * 128;
    int srow = tid >> 1, sseg = (tid & 1) * 16;
    const u16* aSrc = A + (size_t)(m0 + srow) * K + sseg;
    const u16* bSrc = Bt + (size_t)(n0 + srow) * K + sseg;

    f32x4 acc[4][4];
#pragma unroll
    for (int mi = 0; mi < 4; ++mi)
#pragma unroll
        for (int ni = 0; ni < 4; ++ni)
            acc[mi][ni] = (f32x4){0.f, 0.f, 0.f, 0.f};

    for (int kt = 0; kt < K; kt += 32) {
        __syncthreads();
        *(int4*)(As + srow * 40 + sseg)     = *(const int4*)(aSrc + kt);
        *(int4*)(As + srow * 40 + sseg + 8) = *(const int4*)(aSrc + kt + 8);
        *(int4*)(Bs + srow * 40 + sseg)     = *(const int4*)(bSrc + kt);
        *(int4*)(Bs + srow * 40 + sseg + 8) = *(const int4*)(bSrc + kt + 8);
        __syncthreads();
        bfrag af[4], bfv[4];
#pragma unroll
        for (int mi = 0; mi < 4; ++mi)
            af[mi] = *(const bfrag*)(As + (wr * 64 + mi * 16 + r) * 40 + gq * 8);
#pragma unroll
        for (int ni = 0; ni < 4; ++ni)
            bfv[ni] = *(const bfrag*)(Bs + (wc * 64 + ni * 16 + r) * 40 + gq * 8);
#pragma unroll
        for (int mi = 0; mi < 4; ++mi)
#pragma unroll
            for (int ni = 0; ni < 4; ++ni)
                acc[mi][ni] = __builtin_amdgcn_mfma_f32_16x16x32_bf16(af[mi], bfv[ni], acc[mi][ni], 0, 0, 0);
    }

#pragma unroll
    for (int mi = 0; mi < 4; ++mi) {
#pragma unroll
        for (int ni = 0; ni < 4; ++ni) {
            int col = n0 + wc * 64 + ni * 16 + r;
#pragma unroll
            for (int j = 0; j < 4; ++j) {
                int row = m0 + wr * 64 + mi * 16 + gq * 4 + j;
                if (MODE == 0) {
                    obf[(size_t)row * N + col] = f2bf(acc[mi][ni][j]);
                } else {
                    zres[(size_t)row * N + col] += acc[mi][ni][j] + bias[col];
                }
            }
        }
    }
}

// ---------------- V transpose: qkv V-part [key][dh] -> vT [b][h][dh][key] ----------------
__global__ __launch_bounds__(256) void vtrans_kernel(
        const u16* __restrict__ qkv, u16* __restrict__ vT) {
    __shared__ u16 tile[64][65];
    int kt = blockIdx.x, h = blockIdx.y, b = blockIdx.z;
    int tid = threadIdx.x;
    int k0 = kt * 64;
    const u16* src = qkv + (size_t)(b * NTOK + k0) * QKV_N + h * 192 + 128;
    for (int i = tid; i < 4096; i += 256) {
        int rr = i >> 6, cc = i & 63;
        tile[rr][cc] = src[(size_t)rr * QKV_N + cc];
    }
    __syncthreads();
    u16* dst = vT + (size_t)(b * NHEAD + h) * DHEAD * NTOK + k0;
    for (int i = tid; i < 4096; i += 256) {
        int dh = i >> 6, kk = i & 63;
        dst[(size_t)dh * NTOK + kk] = tile[kk][dh];
    }
}

// ---------------- fused attention: per (q-tile 64, head, batch) block; 4 waves x 16 q-rows ----------------
__global__ __launch_bounds__(256) void attn_kernel(
        const u16* __restrict__ qkv, const u16* __restrict__ vT, float* __restrict__ z) {
    __shared__ __attribute__((aligned(16))) u16 P_lds[4][16][584];
    int qt = blockIdx.x, h = blockIdx.y, b = blockIdx.z;
    int tid = threadIdx.x, lane = tid & 63, w = tid >> 6;
    int r = lane & 15, gq = lane >> 4;
    int q0 = qt * 64 + w * 16;

    // Q fragments (A-operand): row = q0 + r, k = dh
    const u16* qbase = qkv + (size_t)(b * NTOK + q0 + r) * QKV_N + h * 192;
    bfrag qf0 = *(const bfrag*)(qbase + gq * 8);
    bfrag qf1 = *(const bfrag*)(qbase + 32 + gq * 8);

    // S = Q @ K^T : 36 column-fragments of 16 keys each, fully in registers
    f32x4 s[36];
#pragma unroll
    for (int kc = 0; kc < 36; ++kc) s[kc] = (f32x4){0.f, 0.f, 0.f, 0.f};
    const u16* kbase = qkv + (size_t)(b * NTOK) * QKV_N + h * 192 + 64;
#pragma unroll
    for (int kc = 0; kc < 36; ++kc) {
        const u16* kp = kbase + (size_t)(kc * 16 + r) * QKV_N + gq * 8;
        bfrag k0 = *(const bfrag*)(kp);
        bfrag k1 = *(const bfrag*)(kp + 32);
        s[kc] = __builtin_amdgcn_mfma_f32_16x16x32_bf16(qf0, k0, s[kc], 0, 0, 0);
        s[kc] = __builtin_amdgcn_mfma_f32_16x16x32_bf16(qf1, k1, s[kc], 0, 0, 0);
    }

    // softmax per q-row: row = gq*4 + j lives in the 16 lanes sharing gq
#pragma unroll
    for (int j = 0; j < 4; ++j) {
        float m = -1e30f;
#pragma unroll
        for (int kc = 0; kc < 36; ++kc) m = fmaxf(m, s[kc][j]);
#pragma unroll
        for (int msk = 1; msk < 16; msk <<= 1) m = fmaxf(m, __shfl_xor(m, msk));
        float sum = 0.f;
#pragma unroll
        for (int kc = 0; kc < 36; ++kc) {
            float p = __expf((s[kc][j] - m) * 0.125f);
            s[kc][j] = p;
            sum += p;
        }
#pragma unroll
        for (int msk = 1; msk < 16; msk <<= 1) sum += __shfl_xor(sum, msk);
        float inv = 1.0f / sum;
#pragma unroll
        for (int kc = 0; kc < 36; ++kc)
            P_lds[w][gq * 4 + j][kc * 16 + r] = f2bf(s[kc][j] * inv);
    }

    // O = P @ V
    f32x4 o[4];
#pragma unroll
    for (int ni = 0; ni < 4; ++ni) o[ni] = (f32x4){0.f, 0.f, 0.f, 0.f};
    const u16* vbase = vT + (size_t)(b * NHEAD + h) * DHEAD * NTOK;
#pragma unroll
    for (int ks = 0; ks < 18; ++ks) {
        bfrag pa = *(const bfrag*)(&P_lds[w][r][ks * 32 + gq * 8]);
#pragma unroll
        for (int ni = 0; ni < 4; ++ni) {
            bfrag vb = *(const bfrag*)(vbase + (size_t)(ni * 16 + r) * NTOK + ks * 32 + gq * 8);
            o[ni] = __builtin_amdgcn_mfma_f32_16x16x32_bf16(pa, vb, o[ni], 0, 0, 0);
        }
    }

    // z += O  (disjoint (b, q-rows, head-cols) per block -> no races)
    float* zb = z + (size_t)(b * NTOK + q0) * DMODEL + h * DHEAD;
#pragma unroll
    for (int ni = 0; ni < 4; ++ni)
#pragma unroll
        for (int j = 0; j < 4; ++j)
            zb[(size_t)(gq * 4 + j) * DMODEL + ni * 16 + r] += o[ni][j];
}

extern "C" void kernel_launch(void* const* d_in, const int* in_sizes, int n_in,
                              void* d_out, int out_size, void* d_ws, size_t ws_size,
                              hipStream_t stream) {
    const float* z_in  = (const float*)d_in[0];
    const float* Wqkv  = (const float*)d_in[1];
    const float* ln1_g = (const float*)d_in[2];
    const float* ln1_b = (const float*)d_in[3];
    const float* Wmlp  = (const float*)d_in[4];
    const float* bmlp  = (const float*)d_in[5];
    const float* ln2_g = (const float*)d_in[6];
    const float* ln2_b = (const float*)d_in[7];
    float* z = (float*)d_out;

    char* ws = (char*)d_ws;
    u16* x_bf   = (u16*)(ws);                  // 18432*768*2   = 28,311,552
    u16* qkv_bf = (u16*)(ws + 28311552);       // 18432*2304*2  = 84,934,656
    u16* vT     = (u16*)(ws + 113246208);      // 32*12*64*576*2= 28,311,552
    u16* wqkvT  = (u16*)(ws + 141557760);      // 2304*768*2    =  3,538,944
    u16* wmlpT  = (u16*)(ws + 145096704);      // 768*768*2     =  1,179,648

    hipMemcpyAsync(z, z_in, (size_t)BN_ROWS * DMODEL * sizeof(float),
                   hipMemcpyDeviceToDevice, stream);

    for (int l = 0; l < L_LAYERS; ++l) {
        transpose_cast_kernel<<<dim3(QKV_N / 64, DMODEL / 64), 256, 0, stream>>>(
            Wqkv + (size_t)l * DMODEL * QKV_N, wqkvT, DMODEL, QKV_N);
        transpose_cast_kernel<<<dim3(DMODEL / 64, DMODEL / 64), 256, 0, stream>>>(
            Wmlp + (size_t)l * DMODEL * DMODEL, wmlpT, DMODEL, DMODEL);

        ln_kernel<<<BN_ROWS / 4, 256, 0, stream>>>(z, ln1_g + l * DMODEL, ln1_b + l * DMODEL, x_bf);

        gemm_kernel<0><<<dim3(QKV_N / 128, BN_ROWS / 128), 256, 0, stream>>>(
            x_bf, wqkvT, BN_ROWS, QKV_N, DMODEL, qkv_bf, nullptr, nullptr);

        vtrans_kernel<<<dim3(NTOK / 64, NHEAD, BATCH), 256, 0, stream>>>(qkv_bf, vT);

        attn_kernel<<<dim3(NTOK / 64, NHEAD, BATCH), 256, 0, stream>>>(qkv_bf, vT, z);

        ln_kernel<<<BN_ROWS / 4, 256, 0, stream>>>(z, ln2_g + l * DMODEL, ln2_b + l * DMODEL, x_bf);

        gemm_kernel<1><<<dim3(DMODEL / 128, BN_ROWS / 128), 256, 0, stream>>>(
            x_bf, wmlpT, BN_ROWS, DMODEL, DMODEL, nullptr, bmlp + l * DMODEL, z);
    }
}

// Round 2
// 4801.003 us; speedup vs baseline: 1.2636x; 1.2636x over previous
//
#include <hip/hip_runtime.h>

typedef unsigned short u16;
typedef short bfrag __attribute__((ext_vector_type(8)));   // 8 bf16 operand frag
typedef float f32x4 __attribute__((ext_vector_type(4)));   // MFMA accumulator

#define L_LAYERS 12
#define BATCH 32
#define NTOK 576
#define DMODEL 768
#define NHEAD 12
#define DHEAD 64
#define BN_ROWS (BATCH * NTOK)   // 18432
#define QKV_N (3 * DMODEL)       // 2304

__device__ __forceinline__ u16 f2bf(float f) {
    union { float f; unsigned u; } x; x.f = f;
    unsigned r = (x.u + 0x7FFFu + ((x.u >> 16) & 1u)) >> 16;
    return (u16)r;
}

__device__ __forceinline__ void gload_lds16(const void* g, void* l) {
    __builtin_amdgcn_global_load_lds(
        (const __attribute__((address_space(1))) void*)g,
        (__attribute__((address_space(3))) void*)l, 16, 0, 0);
}

// ---------------- transpose + fp32->bf16 cast: src[R][C] -> dst[C][R] ----------------
__global__ __launch_bounds__(256) void transpose_cast_kernel(
        const float* __restrict__ src, u16* __restrict__ dst, int R, int C) {
    __shared__ u16 tile[64][65];
    int c0 = blockIdx.x * 64, r0 = blockIdx.y * 64;
    int tid = threadIdx.x;
    for (int i = tid; i < 4096; i += 256) {
        int rr = i >> 6, cc = i & 63;
        tile[rr][cc] = f2bf(src[(size_t)(r0 + rr) * C + c0 + cc]);
    }
    __syncthreads();
    for (int i = tid; i < 4096; i += 256) {
        int cc = i >> 6, rr = i & 63;
        dst[(size_t)(c0 + cc) * R + r0 + rr] = tile[rr][cc];
    }
}

// ---------------- LayerNorm: fp32 z row -> bf16 out row (one row per wave) ----------------
__global__ __launch_bounds__(256) void ln_kernel(
        const float* __restrict__ z, const float* __restrict__ g,
        const float* __restrict__ b, u16* __restrict__ out) {
    int w = threadIdx.x >> 6, lane = threadIdx.x & 63;
    int row = blockIdx.x * 4 + w;
    const float* zr = z + (size_t)row * DMODEL;
    float4 v[3];
    float sum = 0.f, sq = 0.f;
#pragma unroll
    for (int c = 0; c < 3; ++c) {
        v[c] = *(const float4*)(zr + c * 256 + lane * 4);
        sum += v[c].x + v[c].y + v[c].z + v[c].w;
        sq  += v[c].x * v[c].x + v[c].y * v[c].y + v[c].z * v[c].z + v[c].w * v[c].w;
    }
#pragma unroll
    for (int m = 1; m < 64; m <<= 1) {
        sum += __shfl_xor(sum, m);
        sq  += __shfl_xor(sq, m);
    }
    float mean = sum * (1.0f / DMODEL);
    float var  = sq * (1.0f / DMODEL) - mean * mean;
    float inv  = 1.0f / sqrtf(var + 1e-5f);
    u16* orow = out + (size_t)row * DMODEL;
#pragma unroll
    for (int c = 0; c < 3; ++c) {
        int col = c * 256 + lane * 4;
        float4 gg = *(const float4*)(g + col);
        float4 bb = *(const float4*)(b + col);
        ushort4 u;
        u.x = f2bf((v[c].x - mean) * inv * gg.x + bb.x);
        u.y = f2bf((v[c].y - mean) * inv * gg.y + bb.y);
        u.z = f2bf((v[c].z - mean) * inv * gg.z + bb.z);
        u.w = f2bf((v[c].w - mean) * inv * gg.w + bb.w);
        *(ushort4*)(orow + col) = u;
    }
}

// ---------------- bf16 MFMA GEMM: C[M][N] = A[M][K] @ Bt[N][K]^T ----------------
template<int MODE>
__global__ __launch_bounds__(256) void gemm_kernel(
        const u16* __restrict__ A, const u16* __restrict__ Bt,
        int M, int N, int K,
        u16* __restrict__ obf, const float* __restrict__ bias, float* __restrict__ zres) {
    __shared__ __attribute__((aligned(16))) u16 As[128 * 40];
    __shared__ __attribute__((aligned(16))) u16 Bs[128 * 40];
    int tid = threadIdx.x;
    int lane = tid & 63, w = tid >> 6;
    int wr = w >> 1, wc = w & 1;
    int r = lane & 15, gq = lane >> 4;
    int m0 = blockIdx.y * 128, n0 = blockIdx.x * 128;
    int srow = tid >> 1, sseg = (tid & 1) * 16;
    const u16* aSrc = A + (size_t)(m0 + srow) * K + sseg;
    const u16* bSrc = Bt + (size_t)(n0 + srow) * K + sseg;

    f32x4 acc[4][4];
#pragma unroll
    for (int mi = 0; mi < 4; ++mi)
#pragma unroll
        for (int ni = 0; ni < 4; ++ni)
            acc[mi][ni] = (f32x4){0.f, 0.f, 0.f, 0.f};

    for (int kt = 0; kt < K; kt += 32) {
        __syncthreads();
        *(int4*)(As + srow * 40 + sseg)     = *(const int4*)(aSrc + kt);
        *(int4*)(As + srow * 40 + sseg + 8) = *(const int4*)(aSrc + kt + 8);
        *(int4*)(Bs + srow * 40 + sseg)     = *(const int4*)(bSrc + kt);
        *(int4*)(Bs + srow * 40 + sseg + 8) = *(const int4*)(bSrc + kt + 8);
        __syncthreads();
        bfrag af[4], bfv[4];
#pragma unroll
        for (int mi = 0; mi < 4; ++mi)
            af[mi] = *(const bfrag*)(As + (wr * 64 + mi * 16 + r) * 40 + gq * 8);
#pragma unroll
        for (int ni = 0; ni < 4; ++ni)
            bfv[ni] = *(const bfrag*)(Bs + (wc * 64 + ni * 16 + r) * 40 + gq * 8);
#pragma unroll
        for (int mi = 0; mi < 4; ++mi)
#pragma unroll
            for (int ni = 0; ni < 4; ++ni)
                acc[mi][ni] = __builtin_amdgcn_mfma_f32_16x16x32_bf16(af[mi], bfv[ni], acc[mi][ni], 0, 0, 0);
    }

#pragma unroll
    for (int mi = 0; mi < 4; ++mi) {
#pragma unroll
        for (int ni = 0; ni < 4; ++ni) {
            int col = n0 + wc * 64 + ni * 16 + r;
#pragma unroll
            for (int j = 0; j < 4; ++j) {
                int row = m0 + wr * 64 + mi * 16 + gq * 4 + j;
                if (MODE == 0) {
                    obf[(size_t)row * N + col] = f2bf(acc[mi][ni][j]);
                } else {
                    zres[(size_t)row * N + col] += acc[mi][ni][j] + bias[col];
                }
            }
        }
    }
}

// ---------------- V transpose: qkv V-part [key][dh] -> vT [b][h][dh][key] ----------------
__global__ __launch_bounds__(256) void vtrans_kernel(
        const u16* __restrict__ qkv, u16* __restrict__ vT) {
    __shared__ u16 tile[64][65];
    int kt = blockIdx.x, h = blockIdx.y, b = blockIdx.z;
    int tid = threadIdx.x;
    int k0 = kt * 64;
    const u16* src = qkv + (size_t)(b * NTOK + k0) * QKV_N + h * 192 + 128;
    for (int i = tid; i < 4096; i += 256) {
        int rr = i >> 6, cc = i & 63;
        tile[rr][cc] = src[(size_t)rr * QKV_N + cc];
    }
    __syncthreads();
    u16* dst = vT + (size_t)(b * NHEAD + h) * DHEAD * NTOK + k0;
    for (int i = tid; i < 4096; i += 256) {
        int dh = i >> 6, kk = i & 63;
        dst[(size_t)dh * NTOK + kk] = tile[kk][dh];
    }
}

// ---------------- flash attention: per (q-tile 64, head, batch) block; 4 waves x 16 q-rows
//   online softmax over 6 chunks of 96 keys; K chunk staged in LDS (double-buffered,
//   XOR slot-swizzled via pre-swizzled global source); V read direct from vT (L2).
#define KC 96
#define NCHUNK 6
__global__ __launch_bounds__(256, 4) void attn_kernel(
        const u16* __restrict__ qkv, const u16* __restrict__ vT, float* __restrict__ z) {
    __shared__ __attribute__((aligned(16))) u16 Kst[2][KC * 64];
    __shared__ __attribute__((aligned(16))) u16 P_lds[4][16][104];
    int qt = blockIdx.x, h = blockIdx.y, b = blockIdx.z;
    int tid = threadIdx.x, lane = tid & 63, w = tid >> 6;
    int r = lane & 15, gq = lane >> 4;
    int q0 = qt * 64 + w * 16;

    // Q fragments (A-operand): row = q0 + r, k = dh
    const u16* qbase = qkv + (size_t)(b * NTOK + q0 + r) * QKV_N + h * 192;
    bfrag qf0 = *(const bfrag*)(qbase + gq * 8);
    bfrag qf1 = *(const bfrag*)(qbase + 32 + gq * 8);

    // K staging source: wave w stages 24 rows/chunk, 3 x global_load_lds(16B)
    int srow = (w * 24) + (lane >> 3);                 // local row (it adds 8)
    int sslot = (lane & 7) ^ (lane >> 3);              // XOR swizzle (row&7 == lane>>3)
    const u16* ksrc = qkv + (size_t)(b * NTOK + srow) * QKV_N + h * 192 + 64 + sslot * 8;

    const u16* vbase = vT + (size_t)(b * NHEAD + h) * DHEAD * NTOK;
    float* zb = z + (size_t)(b * NTOK + q0) * DMODEL + h * DHEAD;

    float mrun[4], lrun[4];
    f32x4 o[4];
#pragma unroll
    for (int j = 0; j < 4; ++j) { mrun[j] = -1e30f; lrun[j] = 0.f; }
#pragma unroll
    for (int ni = 0; ni < 4; ++ni) o[ni] = (f32x4){0.f, 0.f, 0.f, 0.f};

    // prologue: stage chunk 0 into buf 0
#pragma unroll
    for (int it = 0; it < 3; ++it)
        gload_lds16(ksrc + (size_t)it * 8 * QKV_N, &Kst[0][(w * 24 + it * 8) * 64]);
    __syncthreads();

    for (int c = 0; c < NCHUNK; ++c) {
        int cur = c & 1;
        if (c + 1 < NCHUNK) {
#pragma unroll
            for (int it = 0; it < 3; ++it)
                gload_lds16(ksrc + (size_t)((c + 1) * KC + it * 8) * QKV_N,
                            &Kst[cur ^ 1][(w * 24 + it * 8) * 64]);
        }

        // S chunk = Q @ K^T
        f32x4 s[6];
#pragma unroll
        for (int kc = 0; kc < 6; ++kc) s[kc] = (f32x4){0.f, 0.f, 0.f, 0.f};
        int s0 = gq ^ (r & 7);
#pragma unroll
        for (int kc = 0; kc < 6; ++kc) {
            const u16* kf = &Kst[cur][(kc * 16 + r) * 64];
            bfrag k0 = *(const bfrag*)(kf + s0 * 8);
            bfrag k1 = *(const bfrag*)(kf + (s0 ^ 4) * 8);
            s[kc] = __builtin_amdgcn_mfma_f32_16x16x32_bf16(qf0, k0, s[kc], 0, 0, 0);
            s[kc] = __builtin_amdgcn_mfma_f32_16x16x32_bf16(qf1, k1, s[kc], 0, 0, 0);
        }

        // online softmax update (per q-row j; 16-lane r-group reduction)
        float fac[4];
#pragma unroll
        for (int j = 0; j < 4; ++j) {
            float cm = s[0][j];
#pragma unroll
            for (int kc = 1; kc < 6; ++kc) cm = fmaxf(cm, s[kc][j]);
#pragma unroll
            for (int msk = 1; msk < 16; msk <<= 1) cm = fmaxf(cm, __shfl_xor(cm, msk));
            float nm = fmaxf(mrun[j], cm);
            fac[j] = __expf((mrun[j] - nm) * 0.125f);
            float ps = 0.f;
#pragma unroll
            for (int kc = 0; kc < 6; ++kc) {
                float p = __expf((s[kc][j] - nm) * 0.125f);
                P_lds[w][gq * 4 + j][kc * 16 + r] = f2bf(p);
                ps += p;
            }
#pragma unroll
            for (int msk = 1; msk < 16; msk <<= 1) ps += __shfl_xor(ps, msk);
            lrun[j] = lrun[j] * fac[j] + ps;
            mrun[j] = nm;
        }
#pragma unroll
        for (int ni = 0; ni < 4; ++ni)
#pragma unroll
            for (int j = 0; j < 4; ++j) o[ni][j] *= fac[j];

        // O += P @ V  (V direct from vT, cols c*96 .. +96)
#pragma unroll
        for (int ks = 0; ks < 3; ++ks) {
            bfrag pa = *(const bfrag*)(&P_lds[w][r][ks * 32 + gq * 8]);
#pragma unroll
            for (int ni = 0; ni < 4; ++ni) {
                bfrag vb = *(const bfrag*)(vbase + (size_t)(ni * 16 + r) * NTOK + c * KC + ks * 32 + gq * 8);
                o[ni] = __builtin_amdgcn_mfma_f32_16x16x32_bf16(pa, vb, o[ni], 0, 0, 0);
            }
        }
        __syncthreads();
    }

    // z += O / l   (disjoint (b, q-rows, head-cols) per block -> no races)
    float inv[4];
#pragma unroll
    for (int j = 0; j < 4; ++j) inv[j] = 1.0f / lrun[j];
#pragma unroll
    for (int ni = 0; ni < 4; ++ni)
#pragma unroll
        for (int j = 0; j < 4; ++j)
            zb[(size_t)(gq * 4 + j) * DMODEL + ni * 16 + r] += o[ni][j] * inv[j];
}

extern "C" void kernel_launch(void* const* d_in, const int* in_sizes, int n_in,
                              void* d_out, int out_size, void* d_ws, size_t ws_size,
                              hipStream_t stream) {
    const float* z_in  = (const float*)d_in[0];
    const float* Wqkv  = (const float*)d_in[1];
    const float* ln1_g = (const float*)d_in[2];
    const float* ln1_b = (const float*)d_in[3];
    const float* Wmlp  = (const float*)d_in[4];
    const float* bmlp  = (const float*)d_in[5];
    const float* ln2_g = (const float*)d_in[6];
    const float* ln2_b = (const float*)d_in[7];
    float* z = (float*)d_out;

    char* ws = (char*)d_ws;
    u16* x_bf   = (u16*)(ws);                  // 18432*768*2   = 28,311,552
    u16* qkv_bf = (u16*)(ws + 28311552);       // 18432*2304*2  = 84,934,656
    u16* vT     = (u16*)(ws + 113246208);      // 32*12*64*576*2= 28,311,552
    u16* wqkvT  = (u16*)(ws + 141557760);      // 2304*768*2    =  3,538,944
    u16* wmlpT  = (u16*)(ws + 145096704);      // 768*768*2     =  1,179,648

    hipMemcpyAsync(z, z_in, (size_t)BN_ROWS * DMODEL * sizeof(float),
                   hipMemcpyDeviceToDevice, stream);

    for (int l = 0; l < L_LAYERS; ++l) {
        transpose_cast_kernel<<<dim3(QKV_N / 64, DMODEL / 64), 256, 0, stream>>>(
            Wqkv + (size_t)l * DMODEL * QKV_N, wqkvT, DMODEL, QKV_N);
        transpose_cast_kernel<<<dim3(DMODEL / 64, DMODEL / 64), 256, 0, stream>>>(
            Wmlp + (size_t)l * DMODEL * DMODEL, wmlpT, DMODEL, DMODEL);

        ln_kernel<<<BN_ROWS / 4, 256, 0, stream>>>(z, ln1_g + l * DMODEL, ln1_b + l * DMODEL, x_bf);

        gemm_kernel<0><<<dim3(QKV_N / 128, BN_ROWS / 128), 256, 0, stream>>>(
            x_bf, wqkvT, BN_ROWS, QKV_N, DMODEL, qkv_bf, nullptr, nullptr);

        vtrans_kernel<<<dim3(NTOK / 64, NHEAD, BATCH), 256, 0, stream>>>(qkv_bf, vT);

        attn_kernel<<<dim3(NTOK / 64, NHEAD, BATCH), 256, 0, stream>>>(qkv_bf, vT, z);

        ln_kernel<<<BN_ROWS / 4, 256, 0, stream>>>(z, ln2_g + l * DMODEL, ln2_b + l * DMODEL, x_bf);

        gemm_kernel<1><<<dim3(DMODEL / 128, BN_ROWS / 128), 256, 0, stream>>>(
            x_bf, wmlpT, BN_ROWS, DMODEL, DMODEL, nullptr, bmlp + l * DMODEL, z);
    }
}

// Round 3
// 4501.385 us; speedup vs baseline: 1.3477x; 1.0666x over previous
//
#include <hip/hip_runtime.h>

typedef unsigned short u16;
typedef short bfrag __attribute__((ext_vector_type(8)));   // 8 bf16 operand frag
typedef float f32x4 __attribute__((ext_vector_type(4)));   // MFMA accumulator

#define L_LAYERS 12
#define BATCH 32
#define NTOK 576
#define DMODEL 768
#define NHEAD 12
#define DHEAD 64
#define BN_ROWS (BATCH * NTOK)   // 18432
#define QKV_N (3 * DMODEL)       // 2304

__device__ __forceinline__ u16 f2bf(float f) {
    union { float f; unsigned u; } x; x.f = f;
    unsigned r = (x.u + 0x7FFFu + ((x.u >> 16) & 1u)) >> 16;
    return (u16)r;
}

__device__ __forceinline__ void gload_lds16(const void* g, void* l) {
    __builtin_amdgcn_global_load_lds(
        (const __attribute__((address_space(1))) void*)g,
        (__attribute__((address_space(3))) void*)l, 16, 0, 0);
}

// ---------------- transpose + fp32->bf16 cast: src[R][C] -> dst[C][R] ----------------
__global__ __launch_bounds__(256) void transpose_cast_kernel(
        const float* __restrict__ src, u16* __restrict__ dst, int R, int C) {
    __shared__ u16 tile[64][65];
    int c0 = blockIdx.x * 64, r0 = blockIdx.y * 64;
    int tid = threadIdx.x;
    for (int i = tid; i < 4096; i += 256) {
        int rr = i >> 6, cc = i & 63;
        tile[rr][cc] = f2bf(src[(size_t)(r0 + rr) * C + c0 + cc]);
    }
    __syncthreads();
    for (int i = tid; i < 4096; i += 256) {
        int cc = i >> 6, rr = i & 63;
        dst[(size_t)(c0 + cc) * R + r0 + rr] = tile[rr][cc];
    }
}

// ---------------- LayerNorm: fp32 z row -> bf16 out row (one row per wave) ----------------
__global__ __launch_bounds__(256) void ln_kernel(
        const float* __restrict__ z, const float* __restrict__ g,
        const float* __restrict__ b, u16* __restrict__ out) {
    int w = threadIdx.x >> 6, lane = threadIdx.x & 63;
    int row = blockIdx.x * 4 + w;
    const float* zr = z + (size_t)row * DMODEL;
    float4 v[3];
    float sum = 0.f, sq = 0.f;
#pragma unroll
    for (int c = 0; c < 3; ++c) {
        v[c] = *(const float4*)(zr + c * 256 + lane * 4);
        sum += v[c].x + v[c].y + v[c].z + v[c].w;
        sq  += v[c].x * v[c].x + v[c].y * v[c].y + v[c].z * v[c].z + v[c].w * v[c].w;
    }
#pragma unroll
    for (int m = 1; m < 64; m <<= 1) {
        sum += __shfl_xor(sum, m);
        sq  += __shfl_xor(sq, m);
    }
    float mean = sum * (1.0f / DMODEL);
    float var  = sq * (1.0f / DMODEL) - mean * mean;
    float inv  = 1.0f / sqrtf(var + 1e-5f);
    u16* orow = out + (size_t)row * DMODEL;
#pragma unroll
    for (int c = 0; c < 3; ++c) {
        int col = c * 256 + lane * 4;
        float4 gg = *(const float4*)(g + col);
        float4 bb = *(const float4*)(b + col);
        ushort4 u;
        u.x = f2bf((v[c].x - mean) * inv * gg.x + bb.x);
        u.y = f2bf((v[c].y - mean) * inv * gg.y + bb.y);
        u.z = f2bf((v[c].z - mean) * inv * gg.z + bb.z);
        u.w = f2bf((v[c].w - mean) * inv * gg.w + bb.w);
        *(ushort4*)(orow + col) = u;
    }
}

// ---------------- bf16 MFMA GEMM (m97 structure): C[M][N] = A[M][K] @ Bt[N][K]^T ----------------
// global_load_lds width-16 staging into linear [128][32] LDS tiles; XCD-swizzled grid.
template<int MODE>
__global__ __launch_bounds__(256) void gemm_kernel(
        const u16* __restrict__ A, const u16* __restrict__ Bt,
        int M, int N, int K,
        u16* __restrict__ obf, const float* __restrict__ bias, float* __restrict__ zres) {
    __shared__ __attribute__((aligned(16))) u16 As[128 * 32];
    __shared__ __attribute__((aligned(16))) u16 Bs[128 * 32];
    int tid = threadIdx.x;
    int lane = tid & 63, w = tid >> 6;
    int wr = w >> 1, wc = w & 1;
    int r = lane & 15, gq = lane >> 4;

    // XCD-aware bijective swizzle (gridDim.x*gridDim.y % 8 == 0 for all our launches)
    int nwg = gridDim.x * gridDim.y;
    int lin = blockIdx.y * gridDim.x + blockIdx.x;
    int swz = (lin & 7) * (nwg >> 3) + (lin >> 3);
    int bx = swz % gridDim.x, by = swz / gridDim.x;
    int m0 = by * 128, n0 = bx * 128;

    int srow = tid >> 2;          // 0..63 (4 lanes per row)
    int sseg = (tid & 3) * 8;     // u16 col offset
    const u16* aSrc = A + (size_t)(m0 + srow) * K + sseg;
    const u16* bSrc = Bt + (size_t)(n0 + srow) * K + sseg;
    u16* aDst0 = As + w * 512;            // rows 0..63 (wave-uniform base)
    u16* aDst1 = As + 2048 + w * 512;     // rows 64..127
    u16* bDst0 = Bs + w * 512;
    u16* bDst1 = Bs + 2048 + w * 512;

    f32x4 acc[4][4];
#pragma unroll
    for (int mi = 0; mi < 4; ++mi)
#pragma unroll
        for (int ni = 0; ni < 4; ++ni)
            acc[mi][ni] = (f32x4){0.f, 0.f, 0.f, 0.f};

    for (int kt = 0; kt < K; kt += 32) {
        __syncthreads();
        gload_lds16(aSrc + kt,                    aDst0);
        gload_lds16(aSrc + (size_t)64 * K + kt,   aDst1);
        gload_lds16(bSrc + kt,                    bDst0);
        gload_lds16(bSrc + (size_t)64 * K + kt,   bDst1);
        __syncthreads();
        bfrag af[4], bfv[4];
#pragma unroll
        for (int mi = 0; mi < 4; ++mi)
            af[mi] = *(const bfrag*)(As + (wr * 64 + mi * 16 + r) * 32 + gq * 8);
#pragma unroll
        for (int ni = 0; ni < 4; ++ni)
            bfv[ni] = *(const bfrag*)(Bs + (wc * 64 + ni * 16 + r) * 32 + gq * 8);
#pragma unroll
        for (int mi = 0; mi < 4; ++mi)
#pragma unroll
            for (int ni = 0; ni < 4; ++ni)
                acc[mi][ni] = __builtin_amdgcn_mfma_f32_16x16x32_bf16(af[mi], bfv[ni], acc[mi][ni], 0, 0, 0);
    }

#pragma unroll
    for (int mi = 0; mi < 4; ++mi) {
#pragma unroll
        for (int ni = 0; ni < 4; ++ni) {
            int col = n0 + wc * 64 + ni * 16 + r;
#pragma unroll
            for (int j = 0; j < 4; ++j) {
                int row = m0 + wr * 64 + mi * 16 + gq * 4 + j;
                if (MODE == 0) {
                    obf[(size_t)row * N + col] = f2bf(acc[mi][ni][j]);
                } else {
                    zres[(size_t)row * N + col] += acc[mi][ni][j] + bias[col];
                }
            }
        }
    }
}

// ---------------- V transpose: qkv V-part [key][dh] -> vT [b][h][dh][key] ----------------
__global__ __launch_bounds__(256) void vtrans_kernel(
        const u16* __restrict__ qkv, u16* __restrict__ vT) {
    __shared__ u16 tile[64][65];
    int kt = blockIdx.x, h = blockIdx.y, b = blockIdx.z;
    int tid = threadIdx.x;
    int k0 = kt * 64;
    const u16* src = qkv + (size_t)(b * NTOK + k0) * QKV_N + h * 192 + 128;
    for (int i = tid; i < 4096; i += 256) {
        int rr = i >> 6, cc = i & 63;
        tile[rr][cc] = src[(size_t)rr * QKV_N + cc];
    }
    __syncthreads();
    u16* dst = vT + (size_t)(b * NHEAD + h) * DHEAD * NTOK + k0;
    for (int i = tid; i < 4096; i += 256) {
        int dh = i >> 6, kk = i & 63;
        dst[(size_t)dh * NTOK + kk] = tile[kk][dh];
    }
}

// ---------------- flash attention: per (q-tile 64, head, batch) block; 4 waves x 16 q-rows
//   online softmax over 9 chunks of 64 keys; K chunk double-buffered in LDS
//   (XOR slot-swizzle via pre-swizzled global source); 6 blocks/CU occupancy.
#define KC 64
#define NCHUNK 9
#define SM_C 0.18033688f   // 0.125 * log2(e)
__global__ __launch_bounds__(256, 6) void attn_kernel(
        const u16* __restrict__ qkv, const u16* __restrict__ vT, float* __restrict__ z) {
    __shared__ __attribute__((aligned(16))) u16 Kst[2][KC * 64];
    __shared__ __attribute__((aligned(16))) u16 P_lds[4][16][72];
    int qt = blockIdx.x, h = blockIdx.y, b = blockIdx.z;
    int tid = threadIdx.x, lane = tid & 63, w = tid >> 6;
    int r = lane & 15, gq = lane >> 4;
    int q0 = qt * 64 + w * 16;

    // Q fragments (A-operand): row = q0 + r, k = dh
    const u16* qbase = qkv + (size_t)(b * NTOK + q0 + r) * QKV_N + h * 192;
    bfrag qf0 = *(const bfrag*)(qbase + gq * 8);
    bfrag qf1 = *(const bfrag*)(qbase + 32 + gq * 8);

    // K staging: per call, wave w stages 8 rows (8 threads x 16B per row); 2 calls/chunk.
    int srow8 = w * 8 + (lane >> 3);                   // local row within 32-row half
    int sslot = (lane & 7) ^ (lane >> 3);              // XOR swizzle (row&7 == lane>>3)
    const u16* ksrc = qkv + (size_t)(b * NTOK + srow8) * QKV_N + h * 192 + 64 + sslot * 8;

    const u16* vbase = vT + (size_t)(b * NHEAD + h) * DHEAD * NTOK;
    float* zb = z + (size_t)(b * NTOK + q0) * DMODEL + h * DHEAD;

    float mrun[4], lrun[4];
    f32x4 o[4];
#pragma unroll
    for (int j = 0; j < 4; ++j) { mrun[j] = -1e30f; lrun[j] = 0.f; }
#pragma unroll
    for (int ni = 0; ni < 4; ++ni) o[ni] = (f32x4){0.f, 0.f, 0.f, 0.f};

    // prologue: stage chunk 0 into buf 0
    gload_lds16(ksrc,                           &Kst[0][(w * 8) * 64]);
    gload_lds16(ksrc + (size_t)32 * QKV_N,      &Kst[0][(32 + w * 8) * 64]);
    __syncthreads();

    for (int c = 0; c < NCHUNK; ++c) {
        int cur = c & 1;
        if (c + 1 < NCHUNK) {
            gload_lds16(ksrc + (size_t)((c + 1) * KC) * QKV_N,      &Kst[cur ^ 1][(w * 8) * 64]);
            gload_lds16(ksrc + (size_t)((c + 1) * KC + 32) * QKV_N, &Kst[cur ^ 1][(32 + w * 8) * 64]);
        }

        // S chunk = Q @ K^T  (read through the slot-swizzle involution)
        f32x4 s[4];
#pragma unroll
        for (int kc = 0; kc < 4; ++kc) s[kc] = (f32x4){0.f, 0.f, 0.f, 0.f};
        int s0 = gq ^ (r & 7);
#pragma unroll
        for (int kc = 0; kc < 4; ++kc) {
            const u16* kf = &Kst[cur][(kc * 16 + r) * 64];
            bfrag k0 = *(const bfrag*)(kf + s0 * 8);
            bfrag k1 = *(const bfrag*)(kf + (s0 ^ 4) * 8);
            s[kc] = __builtin_amdgcn_mfma_f32_16x16x32_bf16(qf0, k0, s[kc], 0, 0, 0);
            s[kc] = __builtin_amdgcn_mfma_f32_16x16x32_bf16(qf1, k1, s[kc], 0, 0, 0);
        }

        // online softmax update (per q-row j; 16-lane r-group reduction)
        float fac[4];
#pragma unroll
        for (int j = 0; j < 4; ++j) {
            float cm = fmaxf(fmaxf(s[0][j], s[1][j]), fmaxf(s[2][j], s[3][j]));
#pragma unroll
            for (int msk = 1; msk < 16; msk <<= 1) cm = fmaxf(cm, __shfl_xor(cm, msk));
            float nm = fmaxf(mrun[j], cm);
            fac[j] = exp2f((mrun[j] - nm) * SM_C);
            float ps = 0.f;
#pragma unroll
            for (int kc = 0; kc < 4; ++kc) {
                float p = exp2f((s[kc][j] - nm) * SM_C);
                P_lds[w][gq * 4 + j][kc * 16 + r] = f2bf(p);
                ps += p;
            }
#pragma unroll
            for (int msk = 1; msk < 16; msk <<= 1) ps += __shfl_xor(ps, msk);
            lrun[j] = lrun[j] * fac[j] + ps;
            mrun[j] = nm;
        }
#pragma unroll
        for (int ni = 0; ni < 4; ++ni)
#pragma unroll
            for (int j = 0; j < 4; ++j) o[ni][j] *= fac[j];

        // O += P @ V  (V direct from vT, cols c*64 .. +64)
#pragma unroll
        for (int ks = 0; ks < 2; ++ks) {
            bfrag pa = *(const bfrag*)(&P_lds[w][r][ks * 32 + gq * 8]);
#pragma unroll
            for (int ni = 0; ni < 4; ++ni) {
                bfrag vb = *(const bfrag*)(vbase + (size_t)(ni * 16 + r) * NTOK + c * KC + ks * 32 + gq * 8);
                o[ni] = __builtin_amdgcn_mfma_f32_16x16x32_bf16(pa, vb, o[ni], 0, 0, 0);
            }
        }
        __syncthreads();
    }

    // z += O / l   (disjoint (b, q-rows, head-cols) per block -> no races)
    float inv[4];
#pragma unroll
    for (int j = 0; j < 4; ++j) inv[j] = 1.0f / lrun[j];
#pragma unroll
    for (int ni = 0; ni < 4; ++ni)
#pragma unroll
        for (int j = 0; j < 4; ++j)
            zb[(size_t)(gq * 4 + j) * DMODEL + ni * 16 + r] += o[ni][j] * inv[j];
}

extern "C" void kernel_launch(void* const* d_in, const int* in_sizes, int n_in,
                              void* d_out, int out_size, void* d_ws, size_t ws_size,
                              hipStream_t stream) {
    const float* z_in  = (const float*)d_in[0];
    const float* Wqkv  = (const float*)d_in[1];
    const float* ln1_g = (const float*)d_in[2];
    const float* ln1_b = (const float*)d_in[3];
    const float* Wmlp  = (const float*)d_in[4];
    const float* bmlp  = (const float*)d_in[5];
    const float* ln2_g = (const float*)d_in[6];
    const float* ln2_b = (const float*)d_in[7];
    float* z = (float*)d_out;

    char* ws = (char*)d_ws;
    u16* x_bf   = (u16*)(ws);                  // 18432*768*2   = 28,311,552
    u16* qkv_bf = (u16*)(ws + 28311552);       // 18432*2304*2  = 84,934,656
    u16* vT     = (u16*)(ws + 113246208);      // 32*12*64*576*2= 28,311,552
    u16* wqkvT  = (u16*)(ws + 141557760);      // 2304*768*2    =  3,538,944
    u16* wmlpT  = (u16*)(ws + 145096704);      // 768*768*2     =  1,179,648

    hipMemcpyAsync(z, z_in, (size_t)BN_ROWS * DMODEL * sizeof(float),
                   hipMemcpyDeviceToDevice, stream);

    for (int l = 0; l < L_LAYERS; ++l) {
        transpose_cast_kernel<<<dim3(QKV_N / 64, DMODEL / 64), 256, 0, stream>>>(
            Wqkv + (size_t)l * DMODEL * QKV_N, wqkvT, DMODEL, QKV_N);
        transpose_cast_kernel<<<dim3(DMODEL / 64, DMODEL / 64), 256, 0, stream>>>(
            Wmlp + (size_t)l * DMODEL * DMODEL, wmlpT, DMODEL, DMODEL);

        ln_kernel<<<BN_ROWS / 4, 256, 0, stream>>>(z, ln1_g + l * DMODEL, ln1_b + l * DMODEL, x_bf);

        gemm_kernel<0><<<dim3(QKV_N / 128, BN_ROWS / 128), 256, 0, stream>>>(
            x_bf, wqkvT, BN_ROWS, QKV_N, DMODEL, qkv_bf, nullptr, nullptr);

        vtrans_kernel<<<dim3(NTOK / 64, NHEAD, BATCH), 256, 0, stream>>>(qkv_bf, vT);

        attn_kernel<<<dim3(NTOK / 64, NHEAD, BATCH), 256, 0, stream>>>(qkv_bf, vT, z);

        ln_kernel<<<BN_ROWS / 4, 256, 0, stream>>>(z, ln2_g + l * DMODEL, ln2_b + l * DMODEL, x_bf);

        gemm_kernel<1><<<dim3(DMODEL / 128, BN_ROWS / 128), 256, 0, stream>>>(
            x_bf, wmlpT, BN_ROWS, DMODEL, DMODEL, nullptr, bmlp + l * DMODEL, z);
    }
}

// Round 5
// 4314.901 us; speedup vs baseline: 1.4059x; 1.0432x over previous
//
#include <hip/hip_runtime.h>

typedef unsigned short u16;
typedef short bfrag __attribute__((ext_vector_type(8)));   // 8 bf16 operand frag
typedef float f32x4 __attribute__((ext_vector_type(4)));   // MFMA accumulator

#define L_LAYERS 12
#define BATCH 32
#define NTOK 576
#define DMODEL 768
#define NHEAD 12
#define DHEAD 64
#define BN_ROWS (BATCH * NTOK)   // 18432
#define QKV_N (3 * DMODEL)       // 2304

__device__ __forceinline__ u16 f2bf(float f) {
    union { float f; unsigned u; } x; x.f = f;
    unsigned r = (x.u + 0x7FFFu + ((x.u >> 16) & 1u)) >> 16;
    return (u16)r;
}

__device__ __forceinline__ void gload_lds16(const void* g, void* l) {
    __builtin_amdgcn_global_load_lds(
        (const __attribute__((address_space(1))) void*)g,
        (__attribute__((address_space(3))) void*)l, 16, 0, 0);
}

// ---------------- transpose + fp32->bf16 cast: src[R][C] -> dst[C][R] ----------------
__global__ __launch_bounds__(256) void transpose_cast_kernel(
        const float* __restrict__ src, u16* __restrict__ dst, int R, int C) {
    __shared__ u16 tile[64][65];
    int c0 = blockIdx.x * 64, r0 = blockIdx.y * 64;
    int tid = threadIdx.x;
    for (int i = tid; i < 4096; i += 256) {
        int rr = i >> 6, cc = i & 63;
        tile[rr][cc] = f2bf(src[(size_t)(r0 + rr) * C + c0 + cc]);
    }
    __syncthreads();
    for (int i = tid; i < 4096; i += 256) {
        int cc = i >> 6, rr = i & 63;
        dst[(size_t)(c0 + cc) * R + r0 + rr] = tile[rr][cc];
    }
}

// ---------------- LayerNorm: fp32 z row -> bf16 out row (one row per wave) ----------------
__global__ __launch_bounds__(256) void ln_kernel(
        const float* __restrict__ z, const float* __restrict__ g,
        const float* __restrict__ b, u16* __restrict__ out) {
    int w = threadIdx.x >> 6, lane = threadIdx.x & 63;
    int row = blockIdx.x * 4 + w;
    const float* zr = z + (size_t)row * DMODEL;
    float4 v[3];
    float sum = 0.f, sq = 0.f;
#pragma unroll
    for (int c = 0; c < 3; ++c) {
        v[c] = *(const float4*)(zr + c * 256 + lane * 4);
        sum += v[c].x + v[c].y + v[c].z + v[c].w;
        sq  += v[c].x * v[c].x + v[c].y * v[c].y + v[c].z * v[c].z + v[c].w * v[c].w;
    }
#pragma unroll
    for (int m = 1; m < 64; m <<= 1) {
        sum += __shfl_xor(sum, m);
        sq  += __shfl_xor(sq, m);
    }
    float mean = sum * (1.0f / DMODEL);
    float var  = sq * (1.0f / DMODEL) - mean * mean;
    float inv  = 1.0f / sqrtf(var + 1e-5f);
    u16* orow = out + (size_t)row * DMODEL;
#pragma unroll
    for (int c = 0; c < 3; ++c) {
        int col = c * 256 + lane * 4;
        float4 gg = *(const float4*)(g + col);
        float4 bb = *(const float4*)(b + col);
        ushort4 u;
        u.x = f2bf((v[c].x - mean) * inv * gg.x + bb.x);
        u.y = f2bf((v[c].y - mean) * inv * gg.y + bb.y);
        u.z = f2bf((v[c].z - mean) * inv * gg.z + bb.z);
        u.w = f2bf((v[c].w - mean) * inv * gg.w + bb.w);
        *(ushort4*)(orow + col) = u;
    }
}

// ---------------- bf16 MFMA GEMM (m97 schedule): C[M][N] = A[M][K] @ Bt[N][K]^T ----------------
// Double-buffered LDS, prefetch-before-compute, ONE barrier per K-step.
template<int MODE>
__global__ __launch_bounds__(256) void gemm_kernel(
        const u16* __restrict__ A, const u16* __restrict__ Bt,
        int M, int N, int K,
        u16* __restrict__ obf, const float* __restrict__ bias, float* __restrict__ zres) {
    __shared__ __attribute__((aligned(16))) u16 As[2][128 * 32];
    __shared__ __attribute__((aligned(16))) u16 Bs[2][128 * 32];
    int tid = threadIdx.x;
    int lane = tid & 63, w = tid >> 6;
    int wr = w >> 1, wc = w & 1;
    int r = lane & 15, gq = lane >> 4;

    // XCD-aware bijective swizzle (gridDim.x*gridDim.y % 8 == 0 for all our launches)
    int nwg = gridDim.x * gridDim.y;
    int lin = blockIdx.y * gridDim.x + blockIdx.x;
    int swz = (lin & 7) * (nwg >> 3) + (lin >> 3);
    int bx = swz % gridDim.x, by = swz / gridDim.x;
    int m0 = by * 128, n0 = bx * 128;

    int srow = tid >> 2;          // 0..63 (4 lanes per row)
    int sseg = (tid & 3) * 8;     // u16 col offset
    const u16* aSrc = A + (size_t)(m0 + srow) * K + sseg;
    const u16* bSrc = Bt + (size_t)(n0 + srow) * K + sseg;

    f32x4 acc[4][4];
#pragma unroll
    for (int mi = 0; mi < 4; ++mi)
#pragma unroll
        for (int ni = 0; ni < 4; ++ni)
            acc[mi][ni] = (f32x4){0.f, 0.f, 0.f, 0.f};

    // prologue: stage tile 0 into buf 0
    gload_lds16(aSrc,                    &As[0][w * 512]);
    gload_lds16(aSrc + (size_t)64 * K,   &As[0][2048 + w * 512]);
    gload_lds16(bSrc,                    &Bs[0][w * 512]);
    gload_lds16(bSrc + (size_t)64 * K,   &Bs[0][2048 + w * 512]);
    __syncthreads();

    int T = K >> 5;
    for (int t = 0; t < T; ++t) {
        if (t + 1 < T) {
            int nb = (t + 1) & 1, nkt = (t + 1) << 5;
            gload_lds16(aSrc + nkt,                    &As[nb][w * 512]);
            gload_lds16(aSrc + (size_t)64 * K + nkt,   &As[nb][2048 + w * 512]);
            gload_lds16(bSrc + nkt,                    &Bs[nb][w * 512]);
            gload_lds16(bSrc + (size_t)64 * K + nkt,   &Bs[nb][2048 + w * 512]);
        }
        int cb = t & 1;
        bfrag af[4], bfv[4];
#pragma unroll
        for (int mi = 0; mi < 4; ++mi)
            af[mi] = *(const bfrag*)(&As[cb][(wr * 64 + mi * 16 + r) * 32 + gq * 8]);
#pragma unroll
        for (int ni = 0; ni < 4; ++ni)
            bfv[ni] = *(const bfrag*)(&Bs[cb][(wc * 64 + ni * 16 + r) * 32 + gq * 8]);
#pragma unroll
        for (int mi = 0; mi < 4; ++mi)
#pragma unroll
            for (int ni = 0; ni < 4; ++ni)
                acc[mi][ni] = __builtin_amdgcn_mfma_f32_16x16x32_bf16(af[mi], bfv[ni], acc[mi][ni], 0, 0, 0);
        __syncthreads();   // waves done reading buf cb; prefetch (vmcnt drain) landed
    }

#pragma unroll
    for (int mi = 0; mi < 4; ++mi) {
#pragma unroll
        for (int ni = 0; ni < 4; ++ni) {
            int col = n0 + wc * 64 + ni * 16 + r;
#pragma unroll
            for (int j = 0; j < 4; ++j) {
                int row = m0 + wr * 64 + mi * 16 + gq * 4 + j;
                if (MODE == 0) {
                    obf[(size_t)row * N + col] = f2bf(acc[mi][ni][j]);
                } else {
                    zres[(size_t)row * N + col] += acc[mi][ni][j] + bias[col];
                }
            }
        }
    }
}

// ---------------- V transpose: qkv V-part [key][dh] -> vT [b][h][dh][key] ----------------
__global__ __launch_bounds__(256) void vtrans_kernel(
        const u16* __restrict__ qkv, u16* __restrict__ vT) {
    __shared__ u16 tile[64][65];
    int kt = blockIdx.x, h = blockIdx.y, b = blockIdx.z;
    int tid = threadIdx.x;
    int k0 = kt * 64;
    const u16* src = qkv + (size_t)(b * NTOK + k0) * QKV_N + h * 192 + 128;
    for (int i = tid; i < 4096; i += 256) {
        int rr = i >> 6, cc = i & 63;
        tile[rr][cc] = src[(size_t)rr * QKV_N + cc];
    }
    __syncthreads();
    u16* dst = vT + (size_t)(b * NHEAD + h) * DHEAD * NTOK + k0;
    for (int i = tid; i < 4096; i += 256) {
        int dh = i >> 6, kk = i & 63;
        dst[(size_t)dh * NTOK + kk] = tile[kk][dh];
    }
}

// ---------------- flash attention: 1-D grid, grouped-XCD swizzle so the 9 q-tile blocks of
//   one (b,h) land on ONE XCD back-to-back -> K/V L2-resident, fetched once per XCD.
//   384 groups = 48 per XCD: i = xcd + 8*(group_in_xcd*9 + qt)  (bijective).
#define KC 64
#define NCHUNK 9
#define SM_C 0.18033688f   // 0.125 * log2(e)
__global__ __launch_bounds__(256, 6) void attn_kernel(
        const u16* __restrict__ qkv, const u16* __restrict__ vT, float* __restrict__ z) {
    __shared__ __attribute__((aligned(16))) u16 Kst[2][KC * 64];
    __shared__ __attribute__((aligned(16))) u16 P_lds[4][16][72];
    // hw id i: xcd = i&7, slot = i>>3 in [0,432); group g = xcd*48 + slot/9, qt = slot%9
    int i = blockIdx.x;
    int slot = i >> 3;
    int qt = slot % 9;
    int g = (i & 7) * 48 + slot / 9;
    int h = g % NHEAD, b = g / NHEAD;
    int tid = threadIdx.x, lane = tid & 63, w = tid >> 6;
    int r = lane & 15, gq = lane >> 4;
    int q0 = qt * 64 + w * 16;

    // Q fragments (A-operand): row = q0 + r, k = dh
    const u16* qbase = qkv + (size_t)(b * NTOK + q0 + r) * QKV_N + h * 192;
    bfrag qf0 = *(const bfrag*)(qbase + gq * 8);
    bfrag qf1 = *(const bfrag*)(qbase + 32 + gq * 8);

    // K staging: per call, wave w stages 8 rows (8 threads x 16B per row); 2 calls/chunk.
    int srow8 = w * 8 + (lane >> 3);                   // local row within 32-row half
    int sslot = (lane & 7) ^ (lane >> 3);              // XOR swizzle (row&7 == lane>>3)
    const u16* ksrc = qkv + (size_t)(b * NTOK + srow8) * QKV_N + h * 192 + 64 + sslot * 8;

    const u16* vbase = vT + (size_t)(b * NHEAD + h) * DHEAD * NTOK;
    float* zb = z + (size_t)(b * NTOK + q0) * DMODEL + h * DHEAD;

    float mrun[4], lrun[4];
    f32x4 o[4];
#pragma unroll
    for (int j = 0; j < 4; ++j) { mrun[j] = -1e30f; lrun[j] = 0.f; }
#pragma unroll
    for (int ni = 0; ni < 4; ++ni) o[ni] = (f32x4){0.f, 0.f, 0.f, 0.f};

    // prologue: stage chunk 0 into buf 0
    gload_lds16(ksrc,                           &Kst[0][(w * 8) * 64]);
    gload_lds16(ksrc + (size_t)32 * QKV_N,      &Kst[0][(32 + w * 8) * 64]);
    __syncthreads();

    for (int c = 0; c < NCHUNK; ++c) {
        int cur = c & 1;
        if (c + 1 < NCHUNK) {
            gload_lds16(ksrc + (size_t)((c + 1) * KC) * QKV_N,      &Kst[cur ^ 1][(w * 8) * 64]);
            gload_lds16(ksrc + (size_t)((c + 1) * KC + 32) * QKV_N, &Kst[cur ^ 1][(32 + w * 8) * 64]);
        }

        // S chunk = Q @ K^T  (read through the slot-swizzle involution)
        f32x4 s[4];
#pragma unroll
        for (int kc = 0; kc < 4; ++kc) s[kc] = (f32x4){0.f, 0.f, 0.f, 0.f};
        int s0 = gq ^ (r & 7);
#pragma unroll
        for (int kc = 0; kc < 4; ++kc) {
            const u16* kf = &Kst[cur][(kc * 16 + r) * 64];
            bfrag k0 = *(const bfrag*)(kf + s0 * 8);
            bfrag k1 = *(const bfrag*)(kf + (s0 ^ 4) * 8);
            s[kc] = __builtin_amdgcn_mfma_f32_16x16x32_bf16(qf0, k0, s[kc], 0, 0, 0);
            s[kc] = __builtin_amdgcn_mfma_f32_16x16x32_bf16(qf1, k1, s[kc], 0, 0, 0);
        }

        // online softmax update (per q-row j; 16-lane r-group reduction)
        float fac[4];
#pragma unroll
        for (int j = 0; j < 4; ++j) {
            float cm = fmaxf(fmaxf(s[0][j], s[1][j]), fmaxf(s[2][j], s[3][j]));
#pragma unroll
            for (int msk = 1; msk < 16; msk <<= 1) cm = fmaxf(cm, __shfl_xor(cm, msk));
            float nm = fmaxf(mrun[j], cm);
            fac[j] = exp2f((mrun[j] - nm) * SM_C);
            float ps = 0.f;
#pragma unroll
            for (int kc = 0; kc < 4; ++kc) {
                float p = exp2f((s[kc][j] - nm) * SM_C);
                P_lds[w][gq * 4 + j][kc * 16 + r] = f2bf(p);
                ps += p;
            }
#pragma unroll
            for (int msk = 1; msk < 16; msk <<= 1) ps += __shfl_xor(ps, msk);
            lrun[j] = lrun[j] * fac[j] + ps;
            mrun[j] = nm;
        }
#pragma unroll
        for (int ni = 0; ni < 4; ++ni)
#pragma unroll
            for (int j = 0; j < 4; ++j) o[ni][j] *= fac[j];

        // O += P @ V  (V direct from vT, cols c*64 .. +64)
#pragma unroll
        for (int ks = 0; ks < 2; ++ks) {
            bfrag pa = *(const bfrag*)(&P_lds[w][r][ks * 32 + gq * 8]);
#pragma unroll
            for (int ni = 0; ni < 4; ++ni) {
                bfrag vb = *(const bfrag*)(vbase + (size_t)(ni * 16 + r) * NTOK + c * KC + ks * 32 + gq * 8);
                o[ni] = __builtin_amdgcn_mfma_f32_16x16x32_bf16(pa, vb, o[ni], 0, 0, 0);
            }
        }
        __syncthreads();
    }

    // z += O / l   (disjoint (b, q-rows, head-cols) per block -> no races)
    float inv[4];
#pragma unroll
    for (int j = 0; j < 4; ++j) inv[j] = 1.0f / lrun[j];
#pragma unroll
    for (int ni = 0; ni < 4; ++ni)
#pragma unroll
        for (int j = 0; j < 4; ++j)
            zb[(size_t)(gq * 4 + j) * DMODEL + ni * 16 + r] += o[ni][j] * inv[j];
}

extern "C" void kernel_launch(void* const* d_in, const int* in_sizes, int n_in,
                              void* d_out, int out_size, void* d_ws, size_t ws_size,
                              hipStream_t stream) {
    const float* z_in  = (const float*)d_in[0];
    const float* Wqkv  = (const float*)d_in[1];
    const float* ln1_g = (const float*)d_in[2];
    const float* ln1_b = (const float*)d_in[3];
    const float* Wmlp  = (const float*)d_in[4];
    const float* bmlp  = (const float*)d_in[5];
    const float* ln2_g = (const float*)d_in[6];
    const float* ln2_b = (const float*)d_in[7];
    float* z = (float*)d_out;

    char* ws = (char*)d_ws;
    u16* x_bf   = (u16*)(ws);                  // 18432*768*2   = 28,311,552
    u16* qkv_bf = (u16*)(ws + 28311552);       // 18432*2304*2  = 84,934,656
    u16* vT     = (u16*)(ws + 113246208);      // 32*12*64*576*2= 28,311,552
    u16* wqkvT  = (u16*)(ws + 141557760);      // 2304*768*2    =  3,538,944
    u16* wmlpT  = (u16*)(ws + 145096704);      // 768*768*2     =  1,179,648

    hipMemcpyAsync(z, z_in, (size_t)BN_ROWS * DMODEL * sizeof(float),
                   hipMemcpyDeviceToDevice, stream);

    for (int l = 0; l < L_LAYERS; ++l) {
        transpose_cast_kernel<<<dim3(QKV_N / 64, DMODEL / 64), 256, 0, stream>>>(
            Wqkv + (size_t)l * DMODEL * QKV_N, wqkvT, DMODEL, QKV_N);
        transpose_cast_kernel<<<dim3(DMODEL / 64, DMODEL / 64), 256, 0, stream>>>(
            Wmlp + (size_t)l * DMODEL * DMODEL, wmlpT, DMODEL, DMODEL);

        ln_kernel<<<BN_ROWS / 4, 256, 0, stream>>>(z, ln1_g + l * DMODEL, ln1_b + l * DMODEL, x_bf);

        gemm_kernel<0><<<dim3(QKV_N / 128, BN_ROWS / 128), 256, 0, stream>>>(
            x_bf, wqkvT, BN_ROWS, QKV_N, DMODEL, qkv_bf, nullptr, nullptr);

        vtrans_kernel<<<dim3(NTOK / 64, NHEAD, BATCH), 256, 0, stream>>>(qkv_bf, vT);

        attn_kernel<<<NTOK / 64 * NHEAD * BATCH, 256, 0, stream>>>(qkv_bf, vT, z);

        ln_kernel<<<BN_ROWS / 4, 256, 0, stream>>>(z, ln2_g + l * DMODEL, ln2_b + l * DMODEL, x_bf);

        gemm_kernel<1><<<dim3(DMODEL / 128, BN_ROWS / 128), 256, 0, stream>>>(
            x_bf, wmlpT, BN_ROWS, DMODEL, DMODEL, nullptr, bmlp + l * DMODEL, z);
    }
}